// Round 1
// baseline (221.441 us; speedup 1.0000x reference)
//
#include <hip/hip_runtime.h>
#include <math.h>

#define NA 3
#define NC 80
#define NCH 85   // NC + 5
#define NG 52
#define MAXG 256

// min(log1p(exp(z)), 100) computed stably: softplus with the reference's -100 log-clip
__device__ __forceinline__ float softplus_clip(float z) {
    float sp = fmaxf(z, 0.0f) + log1pf(expf(-fabsf(z)));
    return fminf(sp, 100.0f);
}

// Sum softplus(conf_logit) over every (b, a, j, i) cell -> noobj BCE numerator (before corrections)
__global__ void conf_sum_kernel(const float* __restrict__ out, float* __restrict__ acc, int total) {
    __shared__ float sdata[256];
    float local = 0.0f;
    for (int n = blockIdx.x * blockDim.x + threadIdx.x; n < total; n += gridDim.x * blockDim.x) {
        int plane = n / (NG * NG);          // b*NA + a
        int cell  = n % (NG * NG);
        int off = (plane * NCH + 4) * (NG * NG) + cell;   // channel 4 = conf
        local += softplus_clip(out[off]);
    }
    sdata[threadIdx.x] = local;
    __syncthreads();
    for (int s = 128; s > 0; s >>= 1) {
        if (threadIdx.x < s) sdata[threadIdx.x] += sdata[threadIdx.x + s];
        __syncthreads();
    }
    if (threadIdx.x == 0) atomicAdd(acc, sdata[0]);
}

// Single block: process all GTs, dedupe obj cells / noobj corrections, gather per-cell preds, combine.
__global__ void gt_kernel(const float* __restrict__ out, const float* __restrict__ gts,
                          const float* __restrict__ conf_acc, float* __restrict__ loss_out,
                          int nGts, int nB) {
    __shared__ int   s_batch[MAXG], s_best[MAXG], s_gi[MAXG], s_gj[MAXG], s_label[MAXG];
    __shared__ float s_gx[MAXG], s_gy[MAXG], s_gw[MAXG], s_gh[MAXG];
    __shared__ unsigned char s_ign[MAXG][NA];   // iou > IGNORE per anchor
    __shared__ float red[8];
    __shared__ int   redi[2];

    const float AW[NA] = {0.05f, 0.12f, 0.28f};
    const float AH[NA] = {0.07f, 0.16f, 0.35f};

    const int t = threadIdx.x;
    if (t < 8) red[t] = 0.0f;
    if (t < 2) redi[t] = 0;

    if (t < nGts) {
        float gx = gts[t * 6 + 2], gy = gts[t * 6 + 3];
        float gw = gts[t * 6 + 4], gh = gts[t * 6 + 5];
        s_batch[t] = (int)gts[t * 6 + 0];
        s_label[t] = (int)gts[t * 6 + 1];
        s_gx[t] = gx; s_gy[t] = gy; s_gw[t] = gw; s_gh[t] = gh;
        s_gi[t] = (int)((float)NG * gx);
        s_gj[t] = (int)((float)NG * gy);
        float best = -1.0f; int bn = 0;
        for (int a = 0; a < NA; ++a) {
            float inter = fminf(gw, AW[a]) * fminf(gh, AH[a]);
            float iou = inter / (gw * gh + AW[a] * AH[a] - inter);
            s_ign[t][a] = (iou > 0.5f) ? 1 : 0;
            if (iou > best) { best = iou; bn = a; }   // first-max tie-break, like argmax
        }
        s_best[t] = bn;
    }
    __syncthreads();

    float l_sx = 0, l_sy = 0, l_sw = 0, l_sh = 0, l_sconf = 0, l_scls = 0, l_csum = 0;
    int   l_nobj = 0, l_ccount = 0;

    if (t < nGts) {
        const int b = s_batch[t], bn = s_best[t], gi = s_gi[t], gj = s_gj[t];

        // obj-cell owner: last write wins (XLA CPU scatter applies updates in order)
        bool obj_owner = true;
        for (int u = t + 1; u < nGts; ++u) {
            if (s_batch[u] == b && s_best[u] == bn && s_gi[u] == gi && s_gj[u] == gj) {
                obj_owner = false; break;
            }
        }
        if (obj_owner) {
            l_nobj = 1;
            const float* base = out + (size_t)((b * NA + bn) * NCH) * (NG * NG) + gj * NG + gi;
            float p0 = base[0];
            float p1 = base[(size_t)1 * NG * NG];
            float p2 = base[(size_t)2 * NG * NG];
            float p3 = base[(size_t)3 * NG * NG];
            float p4 = base[(size_t)4 * NG * NG];
            float gxs = (float)NG * s_gx[t]; float txs = gxs - floorf(gxs);
            float gys = (float)NG * s_gy[t]; float tys = gys - floorf(gys);
            float xs = 1.0f / (1.0f + expf(-p0));
            float ys = 1.0f / (1.0f + expf(-p1));
            l_sx = (xs - txs) * (xs - txs);
            l_sy = (ys - tys) * (ys - tys);
            float ltw = logf(s_gw[t] / AW[bn]);
            float lth = logf(s_gh[t] / AH[bn]);
            l_sw = (p2 - ltw) * (p2 - ltw);
            l_sh = (p3 - lth) * (p3 - lth);
            l_sconf = softplus_clip(-p4);           // -log(sigmoid(conf)) at obj (tconf=1)
            const int lab = s_label[t];
            float cls = 0.0f;
            for (int c = 0; c < NC; ++c) {
                float w = base[(size_t)(5 + c) * (NG * NG)];
                cls += softplus_clip(c == lab ? -w : w);
            }
            l_scls = cls;
        }

        // column owner: first occurrence of (batch, gj, gi); enumerate cleared noobj cell-anchors
        bool col_owner = true;
        for (int u = 0; u < t; ++u) {
            if (s_batch[u] == b && s_gi[u] == gi && s_gj[u] == gj) { col_owner = false; break; }
        }
        if (col_owner) {
            for (int a = 0; a < NA; ++a) {
                bool cleared = false;
                for (int u = t; u < nGts; ++u) {
                    if (s_batch[u] == b && s_gi[u] == gi && s_gj[u] == gj) {
                        if (s_ign[u][a] || s_best[u] == a) { cleared = true; break; }
                    }
                }
                if (cleared) {
                    l_ccount += 1;
                    float w = out[(size_t)((b * NA + a) * NCH + 4) * (NG * NG) + gj * NG + gi];
                    l_csum += softplus_clip(w);
                }
            }
        }
    }

    atomicAdd(&red[0], l_sx);
    atomicAdd(&red[1], l_sy);
    atomicAdd(&red[2], l_sw);
    atomicAdd(&red[3], l_sh);
    atomicAdd(&red[4], l_sconf);
    atomicAdd(&red[5], l_scls);
    atomicAdd(&red[6], l_csum);
    atomicAdd(&redi[0], l_nobj);
    atomicAdd(&redi[1], l_ccount);
    __syncthreads();

    if (t == 0) {
        float nObjF   = fmaxf((float)redi[0], 1.0f);
        int   total   = nB * NA * NG * NG;
        float noobjN  = fmaxf((float)(total - redi[1]), 1.0f);
        float confTot = *conf_acc;
        float loss_xy   = (red[0] + red[1]) / nObjF;
        float loss_wh   = (red[2] + red[3]) / nObjF;
        float loss_conf = 1.0f * red[4] / nObjF + 100.0f * (confTot - red[6]) / noobjN;
        float loss_cls  = red[5] / fmaxf((float)redi[0] * (float)NC, 1.0f);
        loss_out[0] = loss_xy + loss_wh + loss_conf + loss_cls;
    }
}

extern "C" void kernel_launch(void* const* d_in, const int* in_sizes, int n_in,
                              void* d_out, int out_size, void* d_ws, size_t ws_size,
                              hipStream_t stream) {
    const float* out = (const float*)d_in[0];
    const float* gts = (const float*)d_in[1];
    int nGts = in_sizes[1] / 6;
    if (nGts > MAXG) nGts = MAXG;
    int nB = in_sizes[0] / (NA * NCH * NG * NG);
    float* acc = (float*)d_ws;

    hipMemsetAsync(acc, 0, sizeof(float), stream);

    int total = nB * NA * NG * NG;
    int blocks = (total + 255) / 256;
    conf_sum_kernel<<<blocks, 256, 0, stream>>>(out, acc, total);
    gt_kernel<<<1, 256, 0, stream>>>(out, gts, acc, (float*)d_out, nGts, nB);
}

// Round 2
// 158.659 us; speedup vs baseline: 1.3957x; 1.3957x over previous
//
#include <hip/hip_runtime.h>
#include <math.h>

#define NA 3
#define NC 80
#define NCH 85   // NC + 5
#define NG 52
#define NGG (NG * NG)
#define MAXG 256

// ws layout in 4-byte units
#define WS_NOBJ   0
#define WS_NCLR   1
#define WS_RED    2                    // red[0..7]; red[7] = total conf softplus sum
#define WS_OFF    16                   // obj entry base offsets (int), MAXG
#define WS_LAB    (WS_OFF + MAXG)      // obj entry labels (int)
#define WS_TXS    (WS_LAB + MAXG)
#define WS_TYS    (WS_TXS + MAXG)
#define WS_LTW    (WS_TYS + MAXG)
#define WS_LTH    (WS_LTW + MAXG)
#define WS_CLR    (WS_LTH + MAXG)      // cleared noobj conf offsets (int), 3*MAXG

// min(log1p(exp(z)), 100): softplus with the reference's -100 log-clip
__device__ __forceinline__ float softplus_clip(float z) {
    float sp = fmaxf(z, 0.0f) + log1pf(expf(-fabsf(z)));
    return fminf(sp, 100.0f);
}

// 1 block: dedupe GTs in LDS, emit compacted work lists + zeroed accumulators.
__global__ void prep_kernel(const float* __restrict__ gts, int* __restrict__ wsi,
                            float* __restrict__ wsf, int nGts) {
    __shared__ int s_batch[MAXG], s_best[MAXG], s_gi[MAXG], s_gj[MAXG];
    __shared__ unsigned char s_ign[MAXG][NA];
    __shared__ int cnt[2];

    const float AW[NA] = {0.05f, 0.12f, 0.28f};
    const float AH[NA] = {0.07f, 0.16f, 0.35f};

    const int t = threadIdx.x;
    if (t < 2) cnt[t] = 0;
    if (t < 8) wsf[WS_RED + t] = 0.0f;

    float gx = 0, gy = 0, gw = 0, gh = 0;
    int lab = 0;
    if (t < nGts) {
        gx = gts[t * 6 + 2]; gy = gts[t * 6 + 3];
        gw = gts[t * 6 + 4]; gh = gts[t * 6 + 5];
        s_batch[t] = (int)gts[t * 6 + 0];
        lab = (int)gts[t * 6 + 1];
        s_gi[t] = (int)((float)NG * gx);
        s_gj[t] = (int)((float)NG * gy);
        float best = -1.0f; int bn = 0;
        for (int a = 0; a < NA; ++a) {
            float inter = fminf(gw, AW[a]) * fminf(gh, AH[a]);
            float iou = inter / (gw * gh + AW[a] * AH[a] - inter);
            s_ign[t][a] = (iou > 0.5f) ? 1 : 0;
            if (iou > best) { best = iou; bn = a; }   // first-max, like argmax
        }
        s_best[t] = bn;
    }
    __syncthreads();

    if (t < nGts) {
        const int b = s_batch[t], bn = s_best[t], gi = s_gi[t], gj = s_gj[t];

        // obj-cell owner: last write wins (scatter applies updates in order)
        bool obj_owner = true;
        for (int u = t + 1; u < nGts; ++u) {
            if (s_batch[u] == b && s_best[u] == bn && s_gi[u] == gi && s_gj[u] == gj) {
                obj_owner = false; break;
            }
        }
        if (obj_owner) {
            int e = atomicAdd(&cnt[0], 1);
            wsi[WS_OFF + e] = ((b * NA + bn) * NCH) * NGG + gj * NG + gi;
            wsi[WS_LAB + e] = lab;
            float gxs = (float)NG * gx; wsf[WS_TXS + e] = gxs - floorf(gxs);
            float gys = (float)NG * gy; wsf[WS_TYS + e] = gys - floorf(gys);
            wsf[WS_LTW + e] = logf(gw / AW[bn]);
            wsf[WS_LTH + e] = logf(gh / AH[bn]);
        }

        // column owner: first occurrence of (batch, gj, gi)
        bool col_owner = true;
        for (int u = 0; u < t; ++u) {
            if (s_batch[u] == b && s_gi[u] == gi && s_gj[u] == gj) { col_owner = false; break; }
        }
        if (col_owner) {
            for (int a = 0; a < NA; ++a) {
                bool cleared = false;
                for (int u = t; u < nGts; ++u) {
                    if (s_batch[u] == b && s_gi[u] == gi && s_gj[u] == gj) {
                        if (s_ign[u][a] || s_best[u] == a) { cleared = true; break; }
                    }
                }
                if (cleared) {
                    int k = atomicAdd(&cnt[1], 1);
                    wsi[WS_CLR + k] = ((b * NA + a) * NCH + 4) * NGG + gj * NG + gi;
                }
            }
        }
    }
    __syncthreads();
    if (t == 0) { wsi[WS_NOBJ] = cnt[0]; wsi[WS_NCLR] = cnt[1]; }
}

// Wide fused kernel: flat work = [conf-plane sum | obj gather items | noobj corrections]
__global__ void fused_kernel(const float* __restrict__ out, int* __restrict__ wsi,
                             float* __restrict__ wsf, int nconf) {
    __shared__ float sred[8];
    if (threadIdx.x < 8) sred[threadIdx.x] = 0.0f;
    __syncthreads();

    const int nObj = wsi[WS_NOBJ];
    const int nClr = wsi[WS_NCLR];
    const int n = blockIdx.x * blockDim.x + threadIdx.x;

    float val = 0.0f; int slot = -1;
    if (n < nconf) {
        int plane = n / NGG, cell = n % NGG;
        val = softplus_clip(out[(plane * NCH + 4) * NGG + cell]);
        slot = 7;
    } else {
        int m = n - nconf;
        if (m < nObj * NCH) {
            int e = m / NCH, c = m % NCH;
            int base = wsi[WS_OFF + e];
            if (c == 0) {
                float p = out[base];
                float xs = 1.0f / (1.0f + expf(-p));
                float d = xs - wsf[WS_TXS + e]; val = d * d; slot = 0;
            } else if (c == 1) {
                float p = out[base + 1 * NGG];
                float ys = 1.0f / (1.0f + expf(-p));
                float d = ys - wsf[WS_TYS + e]; val = d * d; slot = 1;
            } else if (c == 2) {
                float d = out[base + 2 * NGG] - wsf[WS_LTW + e]; val = d * d; slot = 2;
            } else if (c == 3) {
                float d = out[base + 3 * NGG] - wsf[WS_LTH + e]; val = d * d; slot = 3;
            } else if (c == 4) {
                val = softplus_clip(-out[base + 4 * NGG]); slot = 4;   // obj conf BCE (t=1)
            } else {
                int cc = c - 5;
                float w = out[base + (size_t)(5 + cc) * NGG];
                val = softplus_clip(cc == wsi[WS_LAB + e] ? -w : w); slot = 5;
            }
        } else {
            int k = m - nObj * NCH;
            if (k < nClr) {
                val = softplus_clip(out[wsi[WS_CLR + k]]); slot = 6;
            }
        }
    }

    if (slot >= 0) atomicAdd(&sred[slot], val);
    __syncthreads();
    if (threadIdx.x < 8 && sred[threadIdx.x] != 0.0f)
        atomicAdd(&wsf[WS_RED + threadIdx.x], sred[threadIdx.x]);
}

__global__ void final_kernel(const int* __restrict__ wsi, const float* __restrict__ wsf,
                             float* __restrict__ loss_out, int nB) {
    float r0 = wsf[WS_RED + 0], r1 = wsf[WS_RED + 1], r2 = wsf[WS_RED + 2];
    float r3 = wsf[WS_RED + 3], r4 = wsf[WS_RED + 4], r5 = wsf[WS_RED + 5];
    float r6 = wsf[WS_RED + 6], r7 = wsf[WS_RED + 7];
    int nObj = wsi[WS_NOBJ], nClr = wsi[WS_NCLR];
    float nObjF  = fmaxf((float)nObj, 1.0f);
    int   total  = nB * NA * NGG;
    float noobjN = fmaxf((float)(total - nClr), 1.0f);
    float loss_xy   = (r0 + r1) / nObjF;
    float loss_wh   = (r2 + r3) / nObjF;
    float loss_conf = r4 / nObjF + 100.0f * (r7 - r6) / noobjN;
    float loss_cls  = r5 / fmaxf((float)nObj * (float)NC, 1.0f);
    loss_out[0] = loss_xy + loss_wh + loss_conf + loss_cls;
}

extern "C" void kernel_launch(void* const* d_in, const int* in_sizes, int n_in,
                              void* d_out, int out_size, void* d_ws, size_t ws_size,
                              hipStream_t stream) {
    const float* out = (const float*)d_in[0];
    const float* gts = (const float*)d_in[1];
    int nGts = in_sizes[1] / 6;
    if (nGts > MAXG) nGts = MAXG;
    int nB = in_sizes[0] / (NA * NCH * NGG);
    int* wsi = (int*)d_ws;
    float* wsf = (float*)d_ws;

    int nconf = nB * NA * NGG;
    int work = nconf + nGts * NCH + nGts * NA;   // worst-case bound (nObj<=nGts)

    prep_kernel<<<1, 256, 0, stream>>>(gts, wsi, wsf, nGts);
    fused_kernel<<<(work + 255) / 256, 256, 0, stream>>>(out, wsi, wsf, nconf);
    final_kernel<<<1, 1, 0, stream>>>(wsi, wsf, (float*)d_out, nB);
}

// Round 3
// 26.670 us; speedup vs baseline: 8.3030x; 5.9489x over previous
//
#include <hip/hip_runtime.h>
#include <math.h>

#define NA 3
#define NC 80
#define NCH 85   // NC + 5
#define NG 52
#define NGG (NG * NG)
#define MAXG 256
#define HSZ 1024
#define NCONF_V 676   // NGG / 4

// ws layout in 4-byte units
#define WS_NOBJ   0
#define WS_NCLR   1
#define WS_DONE   2
#define WS_RED    3                    // red[0..7]; red[7] = total conf softplus sum
#define WS_OFF    16                   // obj entry base offsets (int), MAXG
#define WS_LAB    (WS_OFF + MAXG)
#define WS_TXS    (WS_LAB + MAXG)
#define WS_TYS    (WS_TXS + MAXG)
#define WS_LTW    (WS_TYS + MAXG)
#define WS_LTH    (WS_LTW + MAXG)
#define WS_CLR    (WS_LTH + MAXG)      // cleared noobj conf offsets (int), 3*MAXG

// min(log1p(exp(z)), 100): softplus with the reference's -100 log-clip
__device__ __forceinline__ float softplus_clip(float z) {
    float sp = fmaxf(z, 0.0f) + log1pf(expf(-fabsf(z)));
    return fminf(sp, 100.0f);
}

// 1 block: hash-based O(1) dedup of GTs, emit compacted work lists + zeroed accumulators.
__global__ void prep_kernel(const float* __restrict__ gts, int* __restrict__ wsi,
                            float* __restrict__ wsf, int nGts) {
    __shared__ int h_key[HSZ], h_min[HSZ], h_mask[HSZ];
    __shared__ int h_max[HSZ][NA];
    __shared__ int cnt[2];

    const float AW[NA] = {0.05f, 0.12f, 0.28f};
    const float AH[NA] = {0.07f, 0.16f, 0.35f};

    const int t = threadIdx.x;
    for (int i = t; i < HSZ; i += 256) {
        h_key[i] = -1; h_min[i] = 0x7fffffff; h_mask[i] = 0;
        h_max[i][0] = -1; h_max[i][1] = -1; h_max[i][2] = -1;
    }
    if (t < 2) cnt[t] = 0;
    if (t < 8) wsf[WS_RED + t] = 0.0f;
    if (t == 0) wsi[WS_DONE] = 0;
    __syncthreads();

    int slot = -1, bn = 0, b = 0, gi = 0, gj = 0, lab = 0;
    float gx = 0, gy = 0, gw = 0, gh = 0;
    if (t < nGts) {
        gx = gts[t * 6 + 2]; gy = gts[t * 6 + 3];
        gw = gts[t * 6 + 4]; gh = gts[t * 6 + 5];
        b   = (int)gts[t * 6 + 0];
        lab = (int)gts[t * 6 + 1];
        gi = (int)((float)NG * gx);
        gj = (int)((float)NG * gy);
        int mask = 0;
        float best = -1.0f;
        for (int a = 0; a < NA; ++a) {
            float inter = fminf(gw, AW[a]) * fminf(gh, AH[a]);
            float iou = inter / (gw * gh + AW[a] * AH[a] - inter);
            if (iou > 0.5f) mask |= (1 << a);
            if (iou > best) { best = iou; bn = a; }   // first-max, like argmax
        }
        mask |= (1 << bn);   // best anchor also cleared in noobj

        int key = (b * NG + gj) * NG + gi;
        slot = (int)(((unsigned)key * 2654435761u) >> 22) & (HSZ - 1);
        for (;;) {
            int prev = atomicCAS(&h_key[slot], -1, key);
            if (prev == -1 || prev == key) break;
            slot = (slot + 1) & (HSZ - 1);
        }
        atomicMin(&h_min[slot], t);       // first occurrence -> column owner
        atomicMax(&h_max[slot][bn], t);   // last write wins -> obj owner
        atomicOr(&h_mask[slot], mask);    // cleared anchors at this cell
    }
    __syncthreads();

    if (t < nGts) {
        if (h_max[slot][bn] == t) {
            int e = atomicAdd(&cnt[0], 1);
            wsi[WS_OFF + e] = ((b * NA + bn) * NCH) * NGG + gj * NG + gi;
            wsi[WS_LAB + e] = lab;
            float gxs = (float)NG * gx; wsf[WS_TXS + e] = gxs - floorf(gxs);
            float gys = (float)NG * gy; wsf[WS_TYS + e] = gys - floorf(gys);
            wsf[WS_LTW + e] = logf(gw / AW[bn]);
            wsf[WS_LTH + e] = logf(gh / AH[bn]);
        }
        if (h_min[slot] == t) {
            int m = h_mask[slot];
            for (int a = 0; a < NA; ++a) {
                if (m & (1 << a)) {
                    int k = atomicAdd(&cnt[1], 1);
                    wsi[WS_CLR + k] = ((b * NA + a) * NCH + 4) * NGG + gj * NG + gi;
                }
            }
        }
    }
    __syncthreads();
    if (t == 0) { wsi[WS_NOBJ] = cnt[0]; wsi[WS_NCLR] = cnt[1]; }
}

// Wide fused kernel: [conf-plane float4 sum | obj gather items | noobj corrections]
// Last block to finish performs the finalize (no separate launch).
__global__ void fused_kernel(const float* __restrict__ out, int* __restrict__ wsi,
                             float* __restrict__ wsf, int nconfv, int nB) {
    __shared__ float sred[8];
    if (threadIdx.x < 8) sred[threadIdx.x] = 0.0f;
    __syncthreads();

    const int nObj = wsi[WS_NOBJ];
    const int nClr = wsi[WS_NCLR];
    const int n = blockIdx.x * blockDim.x + threadIdx.x;

    float val = 0.0f; int slot = -1;
    if (n < nconfv) {
        int plane = n / NCONF_V, q = n % NCONF_V;
        const float4 v = *(const float4*)(out + (size_t)(plane * NCH + 4) * NGG + q * 4);
        val = softplus_clip(v.x) + softplus_clip(v.y) + softplus_clip(v.z) + softplus_clip(v.w);
        slot = 7;
    } else {
        int m = n - nconfv;
        if (m < nObj * NCH) {
            int e = m / NCH, c = m % NCH;
            int base = wsi[WS_OFF + e];
            if (c == 0) {
                float p = out[base];
                float xs = 1.0f / (1.0f + expf(-p));
                float d = xs - wsf[WS_TXS + e]; val = d * d; slot = 0;
            } else if (c == 1) {
                float p = out[base + 1 * NGG];
                float ys = 1.0f / (1.0f + expf(-p));
                float d = ys - wsf[WS_TYS + e]; val = d * d; slot = 1;
            } else if (c == 2) {
                float d = out[base + 2 * NGG] - wsf[WS_LTW + e]; val = d * d; slot = 2;
            } else if (c == 3) {
                float d = out[base + 3 * NGG] - wsf[WS_LTH + e]; val = d * d; slot = 3;
            } else if (c == 4) {
                val = softplus_clip(-out[base + 4 * NGG]); slot = 4;   // obj conf BCE (t=1)
            } else {
                int cc = c - 5;
                float w = out[base + (size_t)(5 + cc) * NGG];
                val = softplus_clip(cc == wsi[WS_LAB + e] ? -w : w); slot = 5;
            }
        } else {
            int k = m - nObj * NCH;
            if (k < nClr) {
                val = softplus_clip(out[wsi[WS_CLR + k]]); slot = 6;
            }
        }
    }

    if (slot >= 0) atomicAdd(&sred[slot], val);
    __syncthreads();

    if (threadIdx.x == 0) {
        // single thread does all global accumulation -> clean ordering vs the done-counter
        for (int i = 0; i < 8; ++i) {
            float s = sred[i];
            if (s != 0.0f) atomicAdd(&wsf[WS_RED + i], s);
        }
        __threadfence();
        int done = atomicAdd(&wsi[WS_DONE], 1);
        if (done == (int)gridDim.x - 1) {
            __threadfence();
            float r[8];
            for (int i = 0; i < 8; ++i) r[i] = atomicAdd(&wsf[WS_RED + i], 0.0f);  // coherent read
            float nObjF  = fmaxf((float)nObj, 1.0f);
            int   total  = nB * NA * NGG;
            float noobjN = fmaxf((float)(total - nClr), 1.0f);
            float loss_xy   = (r[0] + r[1]) / nObjF;
            float loss_wh   = (r[2] + r[3]) / nObjF;
            float loss_conf = r[4] / nObjF + 100.0f * (r[7] - r[6]) / noobjN;
            float loss_cls  = r[5] / fmaxf((float)nObj * (float)NC, 1.0f);
            ((float*)wsf)[0] = 0.0f;  // no-op slot keep (unused)
            *(float*)(wsi - WS_NOBJ + 0) = *(float*)(wsi); // dummy removed below
        }
    }
}

// NOTE: finalize writes loss to d_out; pass d_out pointer explicitly.
__global__ void fused_kernel2(const float* __restrict__ out, int* __restrict__ wsi,
                              float* __restrict__ wsf, float* __restrict__ loss_out,
                              int nconfv, int nB) {
    __shared__ float sred[8];
    if (threadIdx.x < 8) sred[threadIdx.x] = 0.0f;
    __syncthreads();

    const int nObj = wsi[WS_NOBJ];
    const int nClr = wsi[WS_NCLR];
    const int n = blockIdx.x * blockDim.x + threadIdx.x;

    float val = 0.0f; int slot = -1;
    if (n < nconfv) {
        int plane = n / NCONF_V, q = n % NCONF_V;
        const float4 v = *(const float4*)(out + (size_t)(plane * NCH + 4) * NGG + q * 4);
        val = softplus_clip(v.x) + softplus_clip(v.y) + softplus_clip(v.z) + softplus_clip(v.w);
        slot = 7;
    } else {
        int m = n - nconfv;
        if (m < nObj * NCH) {
            int e = m / NCH, c = m % NCH;
            int base = wsi[WS_OFF + e];
            if (c == 0) {
                float p = out[base];
                float xs = 1.0f / (1.0f + expf(-p));
                float d = xs - wsf[WS_TXS + e]; val = d * d; slot = 0;
            } else if (c == 1) {
                float p = out[base + 1 * NGG];
                float ys = 1.0f / (1.0f + expf(-p));
                float d = ys - wsf[WS_TYS + e]; val = d * d; slot = 1;
            } else if (c == 2) {
                float d = out[base + 2 * NGG] - wsf[WS_LTW + e]; val = d * d; slot = 2;
            } else if (c == 3) {
                float d = out[base + 3 * NGG] - wsf[WS_LTH + e]; val = d * d; slot = 3;
            } else if (c == 4) {
                val = softplus_clip(-out[base + 4 * NGG]); slot = 4;
            } else {
                int cc = c - 5;
                float w = out[base + (size_t)(5 + cc) * NGG];
                val = softplus_clip(cc == wsi[WS_LAB + e] ? -w : w); slot = 5;
            }
        } else {
            int k = m - nObj * NCH;
            if (k < nClr) {
                val = softplus_clip(out[wsi[WS_CLR + k]]); slot = 6;
            }
        }
    }

    if (slot >= 0) atomicAdd(&sred[slot], val);
    __syncthreads();

    if (threadIdx.x == 0) {
        for (int i = 0; i < 8; ++i) {
            float s = sred[i];
            if (s != 0.0f) atomicAdd(&wsf[WS_RED + i], s);
        }
        __threadfence();
        int done = atomicAdd(&wsi[WS_DONE], 1);
        if (done == (int)gridDim.x - 1) {
            __threadfence();
            float r[8];
            for (int i = 0; i < 8; ++i) r[i] = atomicAdd(&wsf[WS_RED + i], 0.0f);
            float nObjF  = fmaxf((float)nObj, 1.0f);
            int   total  = nB * NA * NGG;
            float noobjN = fmaxf((float)(total - nClr), 1.0f);
            float loss_xy   = (r[0] + r[1]) / nObjF;
            float loss_wh   = (r[2] + r[3]) / nObjF;
            float loss_conf = r[4] / nObjF + 100.0f * (r[7] - r[6]) / noobjN;
            float loss_cls  = r[5] / fmaxf((float)nObj * (float)NC, 1.0f);
            loss_out[0] = loss_xy + loss_wh + loss_conf + loss_cls;
        }
    }
}

extern "C" void kernel_launch(void* const* d_in, const int* in_sizes, int n_in,
                              void* d_out, int out_size, void* d_ws, size_t ws_size,
                              hipStream_t stream) {
    const float* out = (const float*)d_in[0];
    const float* gts = (const float*)d_in[1];
    int nGts = in_sizes[1] / 6;
    if (nGts > MAXG) nGts = MAXG;
    int nB = in_sizes[0] / (NA * NCH * NGG);
    int* wsi = (int*)d_ws;
    float* wsf = (float*)d_ws;

    int nconfv = nB * NA * NCONF_V;                       // float4 items over conf planes
    int work = nconfv + nGts * NCH + nGts * NA;           // upper bound (nObj <= nGts)

    prep_kernel<<<1, 256, 0, stream>>>(gts, wsi, wsf, nGts);
    fused_kernel2<<<(work + 255) / 256, 256, 0, stream>>>(out, wsi, wsf, (float*)d_out,
                                                          nconfv, nB);
}

// Round 4
// 18.316 us; speedup vs baseline: 12.0902x; 1.4561x over previous
//
#include <hip/hip_runtime.h>
#include <math.h>

#define NA 3
#define NC 80
#define NCH 85   // NC + 5
#define NG 52
#define NGG (NG * NG)
#define MAXG 256
#define HSZ 512
#define NCONF_V (NGG / 4)   // 676 float4 items per conf plane

// min(log1p(exp(z)), 100): softplus with the reference's -100 log-clip
__device__ __forceinline__ float softplus_clip(float z) {
    float sp = fmaxf(z, 0.0f) + log1pf(expf(-fabsf(z)));
    return fminf(sp, 100.0f);
}

// Single kernel. Every block redundantly performs the GT dedup in its own LDS
// (atomicMin/Max/Or are order-independent -> every block derives identical flags),
// then processes its slice of the flat work list:
//   [ conf-plane float4 softplus | obj gather items (nGts*85) | noobj corrections (nGts*3) ]
// Since the loss is linear in the 8 partial sums and each block knows the
// normalizers from its own prep, each block atomicAdds its weighted contribution
// directly into loss_out[0]. No workspace, no inter-block ordering.
__global__ void yolo_loss_kernel(const float* __restrict__ out, const float* __restrict__ gts,
                                 float* __restrict__ loss_out, int nGts, int nB, int nconfv) {
    __shared__ int h_key[HSZ], h_min[HSZ], h_mask[HSZ];
    __shared__ int h_max[HSZ][NA];
    __shared__ int s_base[MAXG], s_coff[MAXG], s_lab[MAXG], s_clr[MAXG];
    __shared__ float s_txs[MAXG], s_tys[MAXG], s_ltw[MAXG], s_lth[MAXG];
    __shared__ unsigned char s_oo[MAXG];
    __shared__ int s_cnt[2];     // nObj, nClr
    __shared__ float sred[8];

    const float AW[NA] = {0.05f, 0.12f, 0.28f};
    const float AH[NA] = {0.07f, 0.16f, 0.35f};
    const int t = threadIdx.x;

    for (int i = t; i < HSZ; i += 256) {
        h_key[i] = -1; h_min[i] = 0x7fffffff; h_mask[i] = 0;
        h_max[i][0] = -1; h_max[i][1] = -1; h_max[i][2] = -1;
    }
    if (t < 2) s_cnt[t] = 0;
    if (t < 8) sred[t] = 0.0f;
    __syncthreads();

    // ---- redundant prep: hash-dedup the GTs (deterministic across blocks) ----
    int slot = -1, bn = 0;
    if (t < nGts) {
        float gx = gts[t * 6 + 2], gy = gts[t * 6 + 3];
        float gw = gts[t * 6 + 4], gh = gts[t * 6 + 5];
        int b = (int)gts[t * 6 + 0];
        s_lab[t] = (int)gts[t * 6 + 1];
        int gi = (int)((float)NG * gx), gj = (int)((float)NG * gy);
        int mask = 0; float best = -1.0f;
        for (int a = 0; a < NA; ++a) {
            float inter = fminf(gw, AW[a]) * fminf(gh, AH[a]);
            float iou = inter / (gw * gh + AW[a] * AH[a] - inter);
            if (iou > 0.5f) mask |= 1 << a;
            if (iou > best) { best = iou; bn = a; }    // first-max, like argmax
        }
        mask |= 1 << bn;   // best anchor is also cleared in noobj

        int key = (b * NG + gj) * NG + gi;
        slot = (int)(((unsigned)key * 2654435761u) >> 23) & (HSZ - 1);
        for (;;) {
            int prev = atomicCAS(&h_key[slot], -1, key);
            if (prev == -1 || prev == key) break;      // key-consistent regardless of CAS order
            slot = (slot + 1) & (HSZ - 1);
        }
        atomicMin(&h_min[slot], t);        // first occurrence -> column owner
        atomicMax(&h_max[slot][bn], t);    // last write wins -> obj owner per anchor
        atomicOr(&h_mask[slot], mask);     // cleared anchors at this cell

        s_base[t] = ((b * NA + bn) * NCH) * NGG + gj * NG + gi;
        s_coff[t] = (b * NA * NCH + 4) * NGG + gj * NG + gi;   // + a*NCH*NGG per anchor
        float gxs = (float)NG * gx; s_txs[t] = gxs - floorf(gxs);
        float gys = (float)NG * gy; s_tys[t] = gys - floorf(gys);
        s_ltw[t] = logf(gw / AW[bn]);
        s_lth[t] = logf(gh / AH[bn]);
    }
    __syncthreads();
    if (t < nGts) {
        bool oo = (h_max[slot][bn] == t);
        s_oo[t] = oo ? 1 : 0;
        if (oo) atomicAdd(&s_cnt[0], 1);
        int cm = (h_min[slot] == t) ? h_mask[slot] : 0;
        s_clr[t] = cm;
        if (cm) atomicAdd(&s_cnt[1], __popc(cm));
    }
    __syncthreads();

    // ---- flat work slice ----
    const int n = blockIdx.x * 256 + t;
    float val = 0.0f; int rs = -1;
    if (n < nconfv) {
        int plane = n / NCONF_V, q = n % NCONF_V;
        const float4 v = *(const float4*)(out + (plane * NCH + 4) * NGG + q * 4);
        val = softplus_clip(v.x) + softplus_clip(v.y) + softplus_clip(v.z) + softplus_clip(v.w);
        rs = 7;
    } else {
        int m = n - nconfv;
        if (m < nGts * NCH) {
            int g = m / NCH, c = m - g * NCH;
            if (s_oo[g]) {
                int base = s_base[g];
                if (c == 0) {
                    float p = out[base];
                    float xs = 1.0f / (1.0f + expf(-p));
                    float d = xs - s_txs[g]; val = d * d; rs = 0;
                } else if (c == 1) {
                    float p = out[base + NGG];
                    float ys = 1.0f / (1.0f + expf(-p));
                    float d = ys - s_tys[g]; val = d * d; rs = 1;
                } else if (c == 2) {
                    float d = out[base + 2 * NGG] - s_ltw[g]; val = d * d; rs = 2;
                } else if (c == 3) {
                    float d = out[base + 3 * NGG] - s_lth[g]; val = d * d; rs = 3;
                } else if (c == 4) {
                    val = softplus_clip(-out[base + 4 * NGG]); rs = 4;   // obj conf BCE (t=1)
                } else {
                    int cc = c - 5;
                    float w = out[base + (5 + cc) * NGG];
                    val = softplus_clip(cc == s_lab[g] ? -w : w); rs = 5;
                }
            }
        } else {
            int k = m - nGts * NCH;
            if (k < nGts * NA) {
                int g = k / NA, a = k - g * NA;
                if ((s_clr[g] >> a) & 1) {
                    val = softplus_clip(out[s_coff[g] + a * (NCH * NGG)]); rs = 6;
                }
            }
        }
    }
    if (rs >= 0) atomicAdd(&sred[rs], val);
    __syncthreads();

    // ---- per-block weighted contribution straight into the scalar loss ----
    if (t == 0) {
        int nObj = s_cnt[0], nClr = s_cnt[1];
        float nObjF  = fmaxf((float)nObj, 1.0f);
        float noobjN = fmaxf((float)(nB * NA * NGG - nClr), 1.0f);
        float c = (sred[0] + sred[1] + sred[2] + sred[3] + sred[4]) / nObjF
                + 100.0f * (sred[7] - sred[6]) / noobjN
                + sred[5] / fmaxf((float)nObj * (float)NC, 1.0f);
        if (c != 0.0f) atomicAdd(loss_out, c);
    }
}

extern "C" void kernel_launch(void* const* d_in, const int* in_sizes, int n_in,
                              void* d_out, int out_size, void* d_ws, size_t ws_size,
                              hipStream_t stream) {
    const float* out = (const float*)d_in[0];
    const float* gts = (const float*)d_in[1];
    int nGts = in_sizes[1] / 6;
    if (nGts > MAXG) nGts = MAXG;
    int nB = in_sizes[0] / (NA * NCH * NGG);

    int nconfv = nB * NA * NCONF_V;
    int work = nconfv + nGts * NCH + nGts * NA;

    hipMemsetAsync(d_out, 0, sizeof(float), stream);
    yolo_loss_kernel<<<(work + 255) / 256, 256, 0, stream>>>(out, gts, (float*)d_out,
                                                             nGts, nB, nconfv);
}